// Round 1
// baseline (2318.557 us; speedup 1.0000x reference)
//
#include <hip/hip_runtime.h>
#include <hip/hip_bf16.h>
#include <cstdint>

#define B_  4
#define T_  2048
#define C_  768
#define H_  12
#define HD_ 64

typedef float    f32x4  __attribute__((ext_vector_type(4)));
typedef __bf16   bf16x8 __attribute__((ext_vector_type(8)));
typedef uint32_t u32x4  __attribute__((ext_vector_type(4)));

__device__ __forceinline__ uint16_t f2b(float f) {
  uint32_t x = __float_as_uint(f);
  uint32_t r = (x + 0x7fffu + ((x >> 16) & 1u)) >> 16;
  return (uint16_t)r;
}
__device__ __forceinline__ float b2f_lo(uint32_t u) { return __uint_as_float(u << 16); }
__device__ __forceinline__ float b2f_hi(uint32_t u) { return __uint_as_float(u & 0xffff0000u); }
__device__ __forceinline__ uint32_t pk2(float a, float b) {
  return (uint32_t)f2b(a) | ((uint32_t)f2b(b) << 16);
}

// ---------------- fp32 -> bf16 cast (vectorized) ----------------
__global__ void k_cvt(const float* __restrict__ in, uint16_t* __restrict__ out, int n4) {
  int i = blockIdx.x * blockDim.x + threadIdx.x;
  if (i >= n4) return;
  float4 v = ((const float4*)in)[i];
  uint2 o;
  o.x = pk2(v.x, v.y);
  o.y = pk2(v.z, v.w);
  ((uint2*)out)[i] = o;
}

// ------- transpose + cast: in fp32 [R][Cc] -> out bf16 [Cc][R] -------
__global__ void k_tr(const float* __restrict__ in, uint16_t* __restrict__ out, int R, int Cc) {
  __shared__ float tile[32][33];
  int n0 = blockIdx.x * 32, k0 = blockIdx.y * 32;
  int tx = threadIdx.x, ty = threadIdx.y;  // (32,8)
#pragma unroll
  for (int i = 0; i < 32; i += 8)
    tile[ty + i][tx] = in[(size_t)(k0 + ty + i) * Cc + n0 + tx];
  __syncthreads();
#pragma unroll
  for (int i = 0; i < 32; i += 8)
    out[(size_t)(n0 + ty + i) * R + k0 + tx] = f2b(tile[tx][ty + i]);
}

// ---------------- MFMA bf16 GEMM: C = A[M,K] * Bt[N,K]^T + bias ----------------
// EPI 0: write fp32 row-major [M,N].  EPI 1: scatter bf16 into QKV [3,B,H,T,64].
#define LDT 56  // padded LDS stride (bf16 elems); 112B rows -> 16B-aligned, 2-way banks
template <int EPI>
__global__ __launch_bounds__(256, 2) void k_gemm(
    const uint16_t* __restrict__ A, const uint16_t* __restrict__ Bt,
    const float* __restrict__ bias, float* __restrict__ outF,
    uint16_t* __restrict__ outQKV, int M, int N, int K) {
  __shared__ uint16_t As[128 * LDT];
  __shared__ uint16_t Bs[128 * LDT];
  const int tid  = threadIdx.x;
  const int lane = tid & 63;
  const int wave = tid >> 6;
  const int wrow = (wave >> 1) * 64, wcol = (wave & 1) * 64;
  const int rowBase = blockIdx.x * 128, colBase = blockIdx.y * 128;
  const int l16 = lane & 15, kg = lane >> 4;

  f32x4 acc[4][4];
#pragma unroll
  for (int i = 0; i < 4; ++i)
#pragma unroll
    for (int j = 0; j < 4; ++j) acc[i][j] = (f32x4){0.f, 0.f, 0.f, 0.f};

  const int sr  = tid >> 2;         // 0..63
  const int skp = (tid & 3) << 3;   // 0,8,16,24
  const uint16_t* aRow = A + (size_t)(rowBase + sr) * K + skp;
  const uint16_t* bRow = Bt + (size_t)(colBase + sr) * K + skp;
  const size_t rstep = (size_t)64 * K;

  for (int k0 = 0; k0 < K; k0 += 32) {
    __syncthreads();
    u32x4 a0 = *(const u32x4*)(aRow + k0);
    u32x4 a1 = *(const u32x4*)(aRow + rstep + k0);
    u32x4 b0 = *(const u32x4*)(bRow + k0);
    u32x4 b1 = *(const u32x4*)(bRow + rstep + k0);
    *(u32x4*)&As[sr * LDT + skp]        = a0;
    *(u32x4*)&As[(sr + 64) * LDT + skp] = a1;
    *(u32x4*)&Bs[sr * LDT + skp]        = b0;
    *(u32x4*)&Bs[(sr + 64) * LDT + skp] = b1;
    __syncthreads();

    bf16x8 af[4], bfv[4];
#pragma unroll
    for (int mi = 0; mi < 4; ++mi)
      af[mi] = *(const bf16x8*)&As[(wrow + mi * 16 + l16) * LDT + kg * 8];
#pragma unroll
    for (int nj = 0; nj < 4; ++nj)
      bfv[nj] = *(const bf16x8*)&Bs[(wcol + nj * 16 + l16) * LDT + kg * 8];
#pragma unroll
    for (int mi = 0; mi < 4; ++mi)
#pragma unroll
      for (int nj = 0; nj < 4; ++nj)
        acc[mi][nj] = __builtin_amdgcn_mfma_f32_16x16x32_bf16(af[mi], bfv[nj], acc[mi][nj], 0, 0, 0);
  }

  const int rg = lane >> 4;
#pragma unroll
  for (int mi = 0; mi < 4; ++mi)
#pragma unroll
    for (int nj = 0; nj < 4; ++nj) {
      int c = colBase + wcol + nj * 16 + l16;
      float bv = bias[c];
#pragma unroll
      for (int jj = 0; jj < 4; ++jj) {
        int r = rowBase + wrow + mi * 16 + rg * 4 + jj;
        float v = acc[mi][nj][jj] + bv;
        if (EPI == 0) {
          outF[(size_t)r * N + c] = v;
        } else {
          int sel = c / 768;
          int rem = c - sel * 768;
          int head = rem >> 6, d = rem & 63;
          int bb = r >> 11, tt = r & 2047;
          size_t off = (((size_t)sel * (B_ * H_) + bb * H_ + head) * T_ + tt) * HD_ + d;
          outQKV[off] = f2b(v);
        }
      }
    }
}

// ---------------- flash-style causal attention (fp32 vector) ----------------
// grid (8, 12, 4) = (q-block of 256 rows, head, batch); one thread = one q row.
__global__ __launch_bounds__(256, 2) void k_attn(
    const uint16_t* __restrict__ Qb, const uint16_t* __restrict__ Kb,
    const uint16_t* __restrict__ Vb, uint16_t* __restrict__ Y) {
  __shared__ float Ks[64 * 68];
  __shared__ float Vs[64 * 68];
  const int tid = threadIdx.x;
  const int qb = blockIdx.x, h = blockIdx.y, b = blockIdx.z;
  const int qrow = qb * 256 + tid;
  const size_t headBase = ((size_t)(b * H_ + h)) * (size_t)(T_ * HD_);

  float q[64];
  {
    const u32x4* qp = (const u32x4*)(Qb + headBase + (size_t)qrow * HD_);
#pragma unroll
    for (int i = 0; i < 8; ++i) {
      u32x4 u = qp[i];
      int base = i * 8;
      q[base + 0] = b2f_lo(u.x); q[base + 1] = b2f_hi(u.x);
      q[base + 2] = b2f_lo(u.y); q[base + 3] = b2f_hi(u.y);
      q[base + 4] = b2f_lo(u.z); q[base + 5] = b2f_hi(u.z);
      q[base + 6] = b2f_lo(u.w); q[base + 7] = b2f_hi(u.w);
    }
  }
  float o[64];
#pragma unroll
  for (int d = 0; d < 64; ++d) o[d] = 0.f;
  float m_ = -__builtin_inff(), l_ = 0.f;

  const int ntiles = qb * 4 + 4;
  const int sr  = tid >> 2;          // 0..63
  const int scp = (tid & 3) * 16;    // 0,16,32,48

  for (int t = 0; t < ntiles; ++t) {
    const int kvoff = t * 64;
    __syncthreads();
    {
      const uint16_t* kp_ = Kb + headBase + (size_t)(kvoff + sr) * HD_ + scp;
      const uint16_t* vp_ = Vb + headBase + (size_t)(kvoff + sr) * HD_ + scp;
      u32x4 k0 = *(const u32x4*)kp_;
      u32x4 k1 = *(const u32x4*)(kp_ + 8);
      u32x4 v0 = *(const u32x4*)vp_;
      u32x4 v1 = *(const u32x4*)(vp_ + 8);
      float* kd = &Ks[sr * 68 + scp];
      float* vd = &Vs[sr * 68 + scp];
      kd[0] = b2f_lo(k0.x); kd[1] = b2f_hi(k0.x); kd[2] = b2f_lo(k0.y); kd[3] = b2f_hi(k0.y);
      kd[4] = b2f_lo(k0.z); kd[5] = b2f_hi(k0.z); kd[6] = b2f_lo(k0.w); kd[7] = b2f_hi(k0.w);
      kd[8]  = b2f_lo(k1.x); kd[9]  = b2f_hi(k1.x); kd[10] = b2f_lo(k1.y); kd[11] = b2f_hi(k1.y);
      kd[12] = b2f_lo(k1.z); kd[13] = b2f_hi(k1.z); kd[14] = b2f_lo(k1.w); kd[15] = b2f_hi(k1.w);
      vd[0] = b2f_lo(v0.x); vd[1] = b2f_hi(v0.x); vd[2] = b2f_lo(v0.y); vd[3] = b2f_hi(v0.y);
      vd[4] = b2f_lo(v0.z); vd[5] = b2f_hi(v0.z); vd[6] = b2f_lo(v0.w); vd[7] = b2f_hi(v0.w);
      vd[8]  = b2f_lo(v1.x); vd[9]  = b2f_hi(v1.x); vd[10] = b2f_lo(v1.y); vd[11] = b2f_hi(v1.y);
      vd[12] = b2f_lo(v1.z); vd[13] = b2f_hi(v1.z); vd[14] = b2f_lo(v1.w); vd[15] = b2f_hi(v1.w);
    }
    __syncthreads();

    for (int ch = 0; ch < 4; ++ch) {
      const int jb = ch * 16;
      float s[16];
      float cmax = -__builtin_inff();
#pragma unroll
      for (int jc = 0; jc < 16; ++jc) {
        const float* kr = &Ks[(jb + jc) * 68];
        float a0 = 0.f, a1 = 0.f, a2 = 0.f, a3 = 0.f;
#pragma unroll
        for (int d = 0; d < 64; d += 4) {
          f32x4 kv = *(const f32x4*)(kr + d);
          a0 = fmaf(q[d + 0], kv.x, a0);
          a1 = fmaf(q[d + 1], kv.y, a1);
          a2 = fmaf(q[d + 2], kv.z, a2);
          a3 = fmaf(q[d + 3], kv.w, a3);
        }
        float sv = ((a0 + a1) + (a2 + a3)) * 0.125f;
        if (kvoff + jb + jc > qrow) sv = -__builtin_inff();
        s[jc] = sv;
        cmax = fmaxf(cmax, sv);
      }
      if (cmax > -1e37f) {
        float nm = fmaxf(m_, cmax);
        float corr = __expf(m_ - nm);
        l_ *= corr;
#pragma unroll
        for (int d = 0; d < 64; ++d) o[d] *= corr;
        float p[16];
        float ps = 0.f;
#pragma unroll
        for (int jc = 0; jc < 16; ++jc) { p[jc] = __expf(s[jc] - nm); ps += p[jc]; }
        l_ += ps;
#pragma unroll
        for (int jc = 0; jc < 16; ++jc) {
          const float* vr = &Vs[(jb + jc) * 68];
          float pj = p[jc];
#pragma unroll
          for (int d = 0; d < 64; d += 4) {
            f32x4 vv = *(const f32x4*)(vr + d);
            o[d + 0] = fmaf(pj, vv.x, o[d + 0]);
            o[d + 1] = fmaf(pj, vv.y, o[d + 1]);
            o[d + 2] = fmaf(pj, vv.z, o[d + 2]);
            o[d + 3] = fmaf(pj, vv.w, o[d + 3]);
          }
        }
        m_ = nm;
      }
    }
  }

  float inv = 1.0f / l_;
  uint16_t* yp = Y + ((size_t)(b * T_ + qrow)) * C_ + h * HD_;
#pragma unroll
  for (int i = 0; i < 8; ++i) {
    int base = i * 8;
    u32x4 u;
    u.x = pk2(o[base + 0] * inv, o[base + 1] * inv);
    u.y = pk2(o[base + 2] * inv, o[base + 3] * inv);
    u.z = pk2(o[base + 4] * inv, o[base + 5] * inv);
    u.w = pk2(o[base + 6] * inv, o[base + 7] * inv);
    *(u32x4*)(yp + base) = u;
  }
}

extern "C" void kernel_launch(void* const* d_in, const int* in_sizes, int n_in,
                              void* d_out, int out_size, void* d_ws, size_t ws_size,
                              hipStream_t stream) {
  const float* x      = (const float*)d_in[0];
  const float* W_attn = (const float*)d_in[1];
  const float* b_attn = (const float*)d_in[2];
  const float* W_proj = (const float*)d_in[3];
  const float* b_proj = (const float*)d_in[4];
  float* out = (float*)d_out;

  char* ws = (char*)d_ws;
  uint16_t* xb  = (uint16_t*)(ws);                 // 8192*768 bf16        = 12,582,912 B
  uint16_t* WtA = (uint16_t*)(ws + 12582912);      // 2304*768 bf16        =  3,538,944 B
  uint16_t* WtP = (uint16_t*)(ws + 16121856);      // 768*768 bf16         =  1,179,648 B
  uint16_t* QKV = (uint16_t*)(ws + 17301504);      // 3*4*12*2048*64 bf16  = 37,748,736 B
  uint16_t* Yb  = (uint16_t*)(ws + 55050240);      // 8192*768 bf16        = 12,582,912 B

  uint16_t* Qp = QKV;
  uint16_t* Kp = QKV + 6291456;   // B_*H_*T_*HD_
  uint16_t* Vp = QKV + 12582912;

  k_cvt<<<6144, 256, 0, stream>>>(x, xb, 1572864);
  k_tr<<<dim3(72, 24), dim3(32, 8), 0, stream>>>(W_attn, WtA, 768, 2304);
  k_tr<<<dim3(24, 24), dim3(32, 8), 0, stream>>>(W_proj, WtP, 768, 768);
  k_gemm<1><<<dim3(64, 18), 256, 0, stream>>>(xb, WtA, b_attn, nullptr, QKV, 8192, 2304, 768);
  k_attn<<<dim3(8, 12, 4), 256, 0, stream>>>(Qp, Kp, Vp, Yb);
  k_gemm<0><<<dim3(64, 6), 256, 0, stream>>>(Yb, WtP, b_proj, out, nullptr, 8192, 768, 768);
}

// Round 2
// 286.209 us; speedup vs baseline: 8.1009x; 8.1009x over previous
//
#include <hip/hip_runtime.h>
#include <hip/hip_bf16.h>
#include <cstdint>

#define B_  4
#define T_  2048
#define C_  768
#define H_  12
#define HD_ 64

typedef float    f32x4  __attribute__((ext_vector_type(4)));
typedef __bf16   bf16x8 __attribute__((ext_vector_type(8)));
typedef uint32_t u32x4  __attribute__((ext_vector_type(4)));

__device__ __forceinline__ uint16_t f2b(float f) {
  uint32_t x = __float_as_uint(f);
  uint32_t r = (x + 0x7fffu + ((x >> 16) & 1u)) >> 16;
  return (uint16_t)r;
}
__device__ __forceinline__ float b2f_lo(uint32_t u) { return __uint_as_float(u << 16); }
__device__ __forceinline__ float b2f_hi(uint32_t u) { return __uint_as_float(u & 0xffff0000u); }
__device__ __forceinline__ uint32_t pk2(float a, float b) {
  return (uint32_t)f2b(a) | ((uint32_t)f2b(b) << 16);
}

// ---------------- fp32 -> bf16 cast (vectorized) ----------------
__global__ void k_cvt(const float* __restrict__ in, uint16_t* __restrict__ out, int n4) {
  int i = blockIdx.x * blockDim.x + threadIdx.x;
  if (i >= n4) return;
  float4 v = ((const float4*)in)[i];
  uint2 o;
  o.x = pk2(v.x, v.y);
  o.y = pk2(v.z, v.w);
  ((uint2*)out)[i] = o;
}

// ------- transpose + cast: in fp32 [R][Cc] -> out bf16 [Cc][R] -------
__global__ void k_tr(const float* __restrict__ in, uint16_t* __restrict__ out, int R, int Cc) {
  __shared__ float tile[32][33];
  int n0 = blockIdx.x * 32, k0 = blockIdx.y * 32;
  int tx = threadIdx.x, ty = threadIdx.y;  // (32,8)
#pragma unroll
  for (int i = 0; i < 32; i += 8)
    tile[ty + i][tx] = in[(size_t)(k0 + ty + i) * Cc + n0 + tx];
  __syncthreads();
#pragma unroll
  for (int i = 0; i < 32; i += 8)
    out[(size_t)(n0 + ty + i) * R + k0 + tx] = f2b(tile[tx][ty + i]);
}

// ---------------- MFMA bf16 GEMM: C = A[M,K] * Bt[N,K]^T + bias ----------------
#define LDT 56
template <int EPI>
__global__ __launch_bounds__(256, 2) void k_gemm(
    const uint16_t* __restrict__ A, const uint16_t* __restrict__ Bt,
    const float* __restrict__ bias, float* __restrict__ outF,
    uint16_t* __restrict__ outQKV, int M, int N, int K) {
  __shared__ uint16_t As[128 * LDT];
  __shared__ uint16_t Bs[128 * LDT];
  const int tid  = threadIdx.x;
  const int lane = tid & 63;
  const int wave = tid >> 6;
  const int wrow = (wave >> 1) * 64, wcol = (wave & 1) * 64;
  const int rowBase = blockIdx.x * 128, colBase = blockIdx.y * 128;
  const int l16 = lane & 15, kg = lane >> 4;

  f32x4 acc[4][4];
#pragma unroll
  for (int i = 0; i < 4; ++i)
#pragma unroll
    for (int j = 0; j < 4; ++j) acc[i][j] = (f32x4){0.f, 0.f, 0.f, 0.f};

  const int sr  = tid >> 2;
  const int skp = (tid & 3) << 3;
  const uint16_t* aRow = A + (size_t)(rowBase + sr) * K + skp;
  const uint16_t* bRow = Bt + (size_t)(colBase + sr) * K + skp;
  const size_t rstep = (size_t)64 * K;

  for (int k0 = 0; k0 < K; k0 += 32) {
    __syncthreads();
    u32x4 a0 = *(const u32x4*)(aRow + k0);
    u32x4 a1 = *(const u32x4*)(aRow + rstep + k0);
    u32x4 b0 = *(const u32x4*)(bRow + k0);
    u32x4 b1 = *(const u32x4*)(bRow + rstep + k0);
    *(u32x4*)&As[sr * LDT + skp]        = a0;
    *(u32x4*)&As[(sr + 64) * LDT + skp] = a1;
    *(u32x4*)&Bs[sr * LDT + skp]        = b0;
    *(u32x4*)&Bs[(sr + 64) * LDT + skp] = b1;
    __syncthreads();

    bf16x8 af[4], bfv[4];
#pragma unroll
    for (int mi = 0; mi < 4; ++mi)
      af[mi] = *(const bf16x8*)&As[(wrow + mi * 16 + l16) * LDT + kg * 8];
#pragma unroll
    for (int nj = 0; nj < 4; ++nj)
      bfv[nj] = *(const bf16x8*)&Bs[(wcol + nj * 16 + l16) * LDT + kg * 8];
#pragma unroll
    for (int mi = 0; mi < 4; ++mi)
#pragma unroll
      for (int nj = 0; nj < 4; ++nj)
        acc[mi][nj] = __builtin_amdgcn_mfma_f32_16x16x32_bf16(af[mi], bfv[nj], acc[mi][nj], 0, 0, 0);
  }

  const int rg = lane >> 4;
#pragma unroll
  for (int mi = 0; mi < 4; ++mi)
#pragma unroll
    for (int nj = 0; nj < 4; ++nj) {
      int c = colBase + wcol + nj * 16 + l16;
      float bv = bias[c];
#pragma unroll
      for (int jj = 0; jj < 4; ++jj) {
        int r = rowBase + wrow + mi * 16 + rg * 4 + jj;
        float v = acc[mi][nj][jj] + bv;
        if (EPI == 0) {
          outF[(size_t)r * N + c] = v;
        } else {
          int sel = c / 768;
          int rem = c - sel * 768;
          int head = rem >> 6, d = rem & 63;
          int bb = r >> 11, tt = r & 2047;
          size_t off = (((size_t)sel * (B_ * H_) + bb * H_ + head) * T_ + tt) * HD_ + d;
          outQKV[off] = f2b(v);
        }
      }
    }
}

// ---------------- MFMA flash attention ----------------
// grid (32, 12, 4); block = 4 waves. Each block: 64 q-rows (16/wave), KV tiles of 64.
// LDS rows padded to 72 elems (144 B) -> ds_read_b128/ds_write_b128 are 2-way (free).
#define LDK 72
__global__ __launch_bounds__(256, 4) void k_attn_mfma(
    const uint16_t* __restrict__ Qb, const uint16_t* __restrict__ Kb,
    const uint16_t* __restrict__ Vb, uint16_t* __restrict__ Y) {
  __shared__ __align__(16) uint16_t Ks[64 * LDK];   // [kv][hd]
  __shared__ __align__(16) uint16_t Vs[64 * LDK];   // transposed: [hd][kv]
  __shared__ __align__(16) uint16_t Ps[4][16 * LDK];
  const int tid  = threadIdx.x;
  const int lane = tid & 63;
  const int wq   = tid >> 6;
  const int l16  = lane & 15, kg = lane >> 4;
  const int qb   = (int)gridDim.x - 1 - (int)blockIdx.x;  // biggest blocks first
  const int h = blockIdx.y, b = blockIdx.z;
  const size_t headBase = ((size_t)(b * H_ + h)) * (size_t)(T_ * HD_);
  const int qrow0 = qb * 64 + wq * 16;

  // Q A-fragments (hd = 64 -> 2 K-chunks of 32)
  bf16x8 qf[2];
  {
    const uint16_t* qp = Qb + headBase + (size_t)(qrow0 + l16) * HD_;
    qf[0] = *(const bf16x8*)(qp + kg * 8);
    qf[1] = *(const bf16x8*)(qp + 32 + kg * 8);
  }

  f32x4 o[4];  // O accum: d-block njd -> col = njd*16+l16, rows kg*4+jj
#pragma unroll
  for (int i = 0; i < 4; ++i) o[i] = (f32x4){0.f, 0.f, 0.f, 0.f};
  float m_[4], l_[4];
#pragma unroll
  for (int jj = 0; jj < 4; ++jj) { m_[jj] = -__builtin_inff(); l_[jj] = 0.f; }

  // staging indices
  const int skv = tid >> 2;             // K: row 0..63
  const int sc2 = (tid & 3) * 2;        // K: chunk pair
  const int vkv = tid & 63;             // V: row 0..63
  const int vdb = (tid >> 6) * 2;       // V: chunk pair

  const int ntiles = qb + 1;
  for (int t = 0; t < ntiles; ++t) {
    const int kvoff = t * 64;
    __syncthreads();
    // --- stage K [kv][hd] ---
    {
      const uint16_t* kp = Kb + headBase + (size_t)(kvoff + skv) * HD_ + sc2 * 8;
      u32x4 k0 = *(const u32x4*)kp;
      u32x4 k1 = *(const u32x4*)(kp + 8);
      *(u32x4*)&Ks[skv * LDK + sc2 * 8]       = k0;
      *(u32x4*)&Ks[skv * LDK + (sc2 + 1) * 8] = k1;
    }
    // --- stage V transposed [hd][kv] ---
    {
      const uint16_t* vp = Vb + headBase + (size_t)(kvoff + vkv) * HD_ + vdb * 8;
      union { u32x4 v[2]; uint16_t e[16]; } tmp;
      tmp.v[0] = *(const u32x4*)vp;
      tmp.v[1] = *(const u32x4*)(vp + 8);
#pragma unroll
      for (int i = 0; i < 16; ++i)
        Vs[(vdb * 8 + i) * LDK + vkv] = tmp.e[i];
    }
    __syncthreads();

    // --- S = Q K^T (per wave: 16 q x 64 kv) ---
    f32x4 sm[4];
#pragma unroll
    for (int nj = 0; nj < 4; ++nj) {
      f32x4 acc = (f32x4){0.f, 0.f, 0.f, 0.f};
#pragma unroll
      for (int kc = 0; kc < 2; ++kc) {
        bf16x8 kf = *(const bf16x8*)&Ks[(nj * 16 + l16) * LDK + kc * 32 + kg * 8];
        acc = __builtin_amdgcn_mfma_f32_16x16x32_bf16(qf[kc], kf, acc, 0, 0, 0);
      }
      // scale + causal mask
      int kvg = kvoff + nj * 16 + l16;
#pragma unroll
      for (int jj = 0; jj < 4; ++jj) {
        int qg = qrow0 + kg * 4 + jj;
        float v = acc[jj] * 0.125f;
        acc[jj] = (kvg > qg) ? -__builtin_inff() : v;
      }
      sm[nj] = acc;
    }

    // --- online softmax (row = kg*4+jj; reduce across 16 lanes of group) ---
#pragma unroll
    for (int jj = 0; jj < 4; ++jj) {
      float v = fmaxf(fmaxf(sm[0][jj], sm[1][jj]), fmaxf(sm[2][jj], sm[3][jj]));
      v = fmaxf(v, __shfl_xor(v, 1));
      v = fmaxf(v, __shfl_xor(v, 2));
      v = fmaxf(v, __shfl_xor(v, 4));
      v = fmaxf(v, __shfl_xor(v, 8));
      float mn = fmaxf(m_[jj], v);
      float corr = __expf(m_[jj] - mn);
      m_[jj] = mn;
      float ps = 0.f;
#pragma unroll
      for (int nj = 0; nj < 4; ++nj) {
        float p = __expf(sm[nj][jj] - mn);
        sm[nj][jj] = p;
        ps += p;
      }
      ps += __shfl_xor(ps, 1);
      ps += __shfl_xor(ps, 2);
      ps += __shfl_xor(ps, 4);
      ps += __shfl_xor(ps, 8);
      l_[jj] = l_[jj] * corr + ps;
#pragma unroll
      for (int njd = 0; njd < 4; ++njd) o[njd][jj] *= corr;
    }

    // --- P -> LDS (per-wave buffer), reload as A-fragments ---
    uint16_t* pw = &Ps[wq][0];
#pragma unroll
    for (int nj = 0; nj < 4; ++nj)
#pragma unroll
      for (int jj = 0; jj < 4; ++jj)
        pw[(kg * 4 + jj) * LDK + nj * 16 + l16] = f2b(sm[nj][jj]);

    // --- O += P V ---
#pragma unroll
    for (int kc = 0; kc < 2; ++kc) {
      bf16x8 pa = *(const bf16x8*)&pw[l16 * LDK + kc * 32 + kg * 8];
#pragma unroll
      for (int njd = 0; njd < 4; ++njd) {
        bf16x8 vf = *(const bf16x8*)&Vs[(njd * 16 + l16) * LDK + kc * 32 + kg * 8];
        o[njd] = __builtin_amdgcn_mfma_f32_16x16x32_bf16(pa, vf, o[njd], 0, 0, 0);
      }
    }
  }

  // --- epilogue: O /= l, write bf16 to Y [B,T,C] ---
#pragma unroll
  for (int jj = 0; jj < 4; ++jj) {
    float inv = 1.0f / l_[jj];
    int q = qrow0 + kg * 4 + jj;
    uint16_t* yp = Y + ((size_t)(b * T_ + q)) * C_ + h * HD_;
#pragma unroll
    for (int njd = 0; njd < 4; ++njd)
      yp[njd * 16 + l16] = f2b(o[njd][jj] * inv);
  }
}

extern "C" void kernel_launch(void* const* d_in, const int* in_sizes, int n_in,
                              void* d_out, int out_size, void* d_ws, size_t ws_size,
                              hipStream_t stream) {
  const float* x      = (const float*)d_in[0];
  const float* W_attn = (const float*)d_in[1];
  const float* b_attn = (const float*)d_in[2];
  const float* W_proj = (const float*)d_in[3];
  const float* b_proj = (const float*)d_in[4];
  float* out = (float*)d_out;

  char* ws = (char*)d_ws;
  uint16_t* xb  = (uint16_t*)(ws);
  uint16_t* WtA = (uint16_t*)(ws + 12582912);
  uint16_t* WtP = (uint16_t*)(ws + 16121856);
  uint16_t* QKV = (uint16_t*)(ws + 17301504);
  uint16_t* Yb  = (uint16_t*)(ws + 55050240);

  uint16_t* Qp = QKV;
  uint16_t* Kp = QKV + 6291456;
  uint16_t* Vp = QKV + 12582912;

  k_cvt<<<6144, 256, 0, stream>>>(x, xb, 1572864);
  k_tr<<<dim3(72, 24), dim3(32, 8), 0, stream>>>(W_attn, WtA, 768, 2304);
  k_tr<<<dim3(24, 24), dim3(32, 8), 0, stream>>>(W_proj, WtP, 768, 768);
  k_gemm<1><<<dim3(64, 18), 256, 0, stream>>>(xb, WtA, b_attn, nullptr, QKV, 8192, 2304, 768);
  k_attn_mfma<<<dim3(32, 12, 4), 256, 0, stream>>>(Qp, Kp, Vp, Yb);
  k_gemm<0><<<dim3(64, 6), 256, 0, stream>>>(Yb, WtP, b_proj, out, nullptr, 8192, 768, 768);
}

// Round 3
// 186.178 us; speedup vs baseline: 12.4535x; 1.5373x over previous
//
#include <hip/hip_runtime.h>
#include <hip/hip_bf16.h>
#include <cstdint>

#define B_  4
#define T_  2048
#define C_  768
#define H_  12
#define HD_ 64

#define AS1 __attribute__((address_space(1)))
#define AS3 __attribute__((address_space(3)))

typedef float    f32x4  __attribute__((ext_vector_type(4)));
typedef __bf16   bf16x8 __attribute__((ext_vector_type(8)));
typedef uint32_t u32x4  __attribute__((ext_vector_type(4)));

__device__ __forceinline__ uint16_t f2b(float f) {
  uint32_t x = __float_as_uint(f);
  uint32_t r = (x + 0x7fffu + ((x >> 16) & 1u)) >> 16;
  return (uint16_t)r;
}
__device__ __forceinline__ uint32_t pk2(float a, float b) {
  return (uint32_t)f2b(a) | ((uint32_t)f2b(b) << 16);
}

// ---------------- fp32 -> bf16 cast (vectorized) ----------------
__global__ void k_cvt(const float* __restrict__ in, uint16_t* __restrict__ out, int n4) {
  int i = blockIdx.x * blockDim.x + threadIdx.x;
  if (i >= n4) return;
  float4 v = ((const float4*)in)[i];
  uint2 o;
  o.x = pk2(v.x, v.y);
  o.y = pk2(v.z, v.w);
  ((uint2*)out)[i] = o;
}

// ------- transpose + cast: in fp32 [R][Cc] -> out bf16 [Cc][R] -------
__global__ void k_tr(const float* __restrict__ in, uint16_t* __restrict__ out, int R, int Cc) {
  __shared__ float tile[32][33];
  int n0 = blockIdx.x * 32, k0 = blockIdx.y * 32;
  int tx = threadIdx.x, ty = threadIdx.y;  // (32,8)
#pragma unroll
  for (int i = 0; i < 32; i += 8)
    tile[ty + i][tx] = in[(size_t)(k0 + ty + i) * Cc + n0 + tx];
  __syncthreads();
#pragma unroll
  for (int i = 0; i < 32; i += 8)
    out[(size_t)(n0 + ty + i) * R + k0 + tx] = f2b(tile[tx][ty + i]);
}

// ---------------- MFMA bf16 GEMM: C = A[M,K] * Bt[N,K]^T + bias ----------------
// EPI 0: fp32 [M,N].  EPI 1: scatter bf16 into QKV; Q,K as [B,H,T,64], V as [B,H,64,T].
#define LDT 56
template <int EPI>
__global__ __launch_bounds__(256, 2) void k_gemm(
    const uint16_t* __restrict__ A, const uint16_t* __restrict__ Bt,
    const float* __restrict__ bias, float* __restrict__ outF,
    uint16_t* __restrict__ outQKV, int M, int N, int K) {
  __shared__ uint16_t As[128 * LDT];
  __shared__ uint16_t Bs[128 * LDT];
  const int tid  = threadIdx.x;
  const int lane = tid & 63;
  const int wave = tid >> 6;
  const int wrow = (wave >> 1) * 64, wcol = (wave & 1) * 64;
  const int rowBase = blockIdx.x * 128, colBase = blockIdx.y * 128;
  const int l16 = lane & 15, kg = lane >> 4;

  f32x4 acc[4][4];
#pragma unroll
  for (int i = 0; i < 4; ++i)
#pragma unroll
    for (int j = 0; j < 4; ++j) acc[i][j] = (f32x4){0.f, 0.f, 0.f, 0.f};

  const int sr  = tid >> 2;
  const int skp = (tid & 3) << 3;
  const uint16_t* aRow = A + (size_t)(rowBase + sr) * K + skp;
  const uint16_t* bRow = Bt + (size_t)(colBase + sr) * K + skp;
  const size_t rstep = (size_t)64 * K;

  for (int k0 = 0; k0 < K; k0 += 32) {
    __syncthreads();
    u32x4 a0 = *(const u32x4*)(aRow + k0);
    u32x4 a1 = *(const u32x4*)(aRow + rstep + k0);
    u32x4 b0 = *(const u32x4*)(bRow + k0);
    u32x4 b1 = *(const u32x4*)(bRow + rstep + k0);
    *(u32x4*)&As[sr * LDT + skp]        = a0;
    *(u32x4*)&As[(sr + 64) * LDT + skp] = a1;
    *(u32x4*)&Bs[sr * LDT + skp]        = b0;
    *(u32x4*)&Bs[(sr + 64) * LDT + skp] = b1;
    __syncthreads();

    bf16x8 af[4], bfv[4];
#pragma unroll
    for (int mi = 0; mi < 4; ++mi)
      af[mi] = *(const bf16x8*)&As[(wrow + mi * 16 + l16) * LDT + kg * 8];
#pragma unroll
    for (int nj = 0; nj < 4; ++nj)
      bfv[nj] = *(const bf16x8*)&Bs[(wcol + nj * 16 + l16) * LDT + kg * 8];
#pragma unroll
    for (int mi = 0; mi < 4; ++mi)
#pragma unroll
      for (int nj = 0; nj < 4; ++nj)
        acc[mi][nj] = __builtin_amdgcn_mfma_f32_16x16x32_bf16(af[mi], bfv[nj], acc[mi][nj], 0, 0, 0);
  }

  const int rg = lane >> 4;
#pragma unroll
  for (int mi = 0; mi < 4; ++mi)
#pragma unroll
    for (int nj = 0; nj < 4; ++nj) {
      int c = colBase + wcol + nj * 16 + l16;
      float bv = bias[c];
#pragma unroll
      for (int jj = 0; jj < 4; ++jj) {
        int r = rowBase + wrow + mi * 16 + rg * 4 + jj;
        float v = acc[mi][nj][jj] + bv;
        if (EPI == 0) {
          outF[(size_t)r * N + c] = v;
        } else {
          int sel = c / 768;
          int rem = c - sel * 768;
          int head = rem >> 6, d = rem & 63;
          int bb = r >> 11, tt = r & 2047;
          size_t off;
          if (sel == 2)  // V stored transposed: [B,H,64,T]
            off = (((size_t)2 * (B_ * H_) + bb * H_ + head) * HD_ + d) * T_ + tt;
          else
            off = (((size_t)sel * (B_ * H_) + bb * H_ + head) * T_ + tt) * HD_ + d;
          outQKV[off] = f2b(v);
        }
      }
    }
}

// ---------------- MFMA flash attention, v2 ----------------
// grid (16, 12, 4); block = 4 waves. Block px handles q-blocks {px, 31-px} (64 rows
// each, 16/wave) -> uniform 33 KV-tile visits per block. KV tiles of 64 staged via
// global_load_lds (width 16) into linear 128B-row LDS, double-buffered (2-phase).
// XOR swizzle (slot ^= row&7) applied on the per-lane GLOBAL source and on the
// ds_read_b128 fragment reads (both-sides involution). V comes pre-transposed
// [B,H,64,T] from GEMM1 so both K and V stage identically.
#define LDP 72
__global__ __launch_bounds__(256, 3) void k_attn2(
    const uint16_t* __restrict__ Qb, const uint16_t* __restrict__ Kb,
    const uint16_t* __restrict__ Vb, uint16_t* __restrict__ Y) {
  __shared__ __align__(16) uint16_t Ks[2][64 * 64];
  __shared__ __align__(16) uint16_t Vs[2][64 * 64];
  __shared__ __align__(16) uint16_t Ps[4][16 * LDP];
  const int tid  = threadIdx.x;
  const int lane = tid & 63;
  const int wq   = tid >> 6;
  const int l16  = lane & 15, kg = lane >> 4;
  const int px = blockIdx.x, h = blockIdx.y, b = blockIdx.z;
  const size_t headBase = ((size_t)(b * H_ + h)) * (size_t)(T_ * HD_);

  const int srow0 = wq * 16 + (lane >> 3);  // staging row (j*8 added below)
  const int sslot = lane & 7;               // 16B slot within 128B row

  uint16_t* pw = &Ps[wq][0];

  auto STAGE = [&](int buf, int t) {
    const int kvoff = t * 64;
#pragma unroll
    for (int j = 0; j < 2; ++j) {
      const int r  = srow0 + j * 8;
      const int sw = ((sslot ^ (r & 7)) << 3);  // swizzled elem offset in row
      const uint16_t* srcK = Kb + headBase + (size_t)(kvoff + r) * HD_ + sw;
      const uint16_t* srcV = Vb + headBase + (size_t)r * T_ + kvoff + sw;
      uint16_t* dstK = &Ks[buf][(wq * 16 + j * 8) * 64];
      uint16_t* dstV = &Vs[buf][(wq * 16 + j * 8) * 64];
      __builtin_amdgcn_global_load_lds((const AS1 uint32_t*)srcK, (AS3 uint32_t*)dstK, 16, 0, 0);
      __builtin_amdgcn_global_load_lds((const AS1 uint32_t*)srcV, (AS3 uint32_t*)dstV, 16, 0, 0);
    }
  };

  for (int part = 0; part < 2; ++part) {
    const int qb = part ? (31 - px) : px;
    const int qrow0 = qb * 64 + wq * 16;

    bf16x8 qf[2];
    {
      const uint16_t* qp = Qb + headBase + (size_t)(qrow0 + l16) * HD_;
      qf[0] = *(const bf16x8*)(qp + kg * 8);
      qf[1] = *(const bf16x8*)(qp + 32 + kg * 8);
    }

    f32x4 o[4];
#pragma unroll
    for (int i = 0; i < 4; ++i) o[i] = (f32x4){0.f, 0.f, 0.f, 0.f};
    float m_[4], l_[4];
#pragma unroll
    for (int jj = 0; jj < 4; ++jj) { m_[jj] = -__builtin_inff(); l_[jj] = 0.f; }

    const int nt = qb + 1;
    STAGE(0, 0);
    __syncthreads();
    int cur = 0;

    for (int t = 0; t < nt; ++t) {
      if (t + 1 < nt) STAGE(cur ^ 1, t + 1);

      const uint16_t* KT = &Ks[cur][0];
      const uint16_t* VT = &Vs[cur][0];
      const int kvoff = t * 64;

      // --- S = Q K^T (16 q x 64 kv per wave) ---
      f32x4 sm[4];
#pragma unroll
      for (int nj = 0; nj < 4; ++nj) {
        f32x4 acc = (f32x4){0.f, 0.f, 0.f, 0.f};
#pragma unroll
        for (int kc = 0; kc < 2; ++kc) {
          const int row = nj * 16 + l16;
          const int s = (((kc * 4 + kg) ^ (row & 7)) << 3);
          bf16x8 kf = *(const bf16x8*)&KT[row * 64 + s];
          acc = __builtin_amdgcn_mfma_f32_16x16x32_bf16(qf[kc], kf, acc, 0, 0, 0);
        }
        int kvg = kvoff + nj * 16 + l16;
#pragma unroll
        for (int jj = 0; jj < 4; ++jj) {
          int qg = qrow0 + kg * 4 + jj;
          float v = acc[jj] * 0.125f;
          acc[jj] = (kvg > qg) ? -__builtin_inff() : v;
        }
        sm[nj] = acc;
      }

      // --- online softmax (row = kg*4+jj; reduce across 16 lanes) ---
#pragma unroll
      for (int jj = 0; jj < 4; ++jj) {
        float v = fmaxf(fmaxf(sm[0][jj], sm[1][jj]), fmaxf(sm[2][jj], sm[3][jj]));
        v = fmaxf(v, __shfl_xor(v, 1));
        v = fmaxf(v, __shfl_xor(v, 2));
        v = fmaxf(v, __shfl_xor(v, 4));
        v = fmaxf(v, __shfl_xor(v, 8));
        float mn = fmaxf(m_[jj], v);
        float corr = __expf(m_[jj] - mn);
        m_[jj] = mn;
        float ps = 0.f;
#pragma unroll
        for (int nj = 0; nj < 4; ++nj) {
          float p = __expf(sm[nj][jj] - mn);
          sm[nj][jj] = p;
          ps += p;
        }
        ps += __shfl_xor(ps, 1);
        ps += __shfl_xor(ps, 2);
        ps += __shfl_xor(ps, 4);
        ps += __shfl_xor(ps, 8);
        l_[jj] = l_[jj] * corr + ps;
#pragma unroll
        for (int njd = 0; njd < 4; ++njd) o[njd][jj] *= corr;
      }

      // --- P -> per-wave LDS buffer, reload as A-fragments ---
#pragma unroll
      for (int nj = 0; nj < 4; ++nj)
#pragma unroll
        for (int jj = 0; jj < 4; ++jj)
          pw[(kg * 4 + jj) * LDP + nj * 16 + l16] = f2b(sm[nj][jj]);

      // --- O += P V ---
#pragma unroll
      for (int kc = 0; kc < 2; ++kc) {
        bf16x8 pa = *(const bf16x8*)&pw[l16 * LDP + kc * 32 + kg * 8];
#pragma unroll
        for (int njd = 0; njd < 4; ++njd) {
          const int row = njd * 16 + l16;
          const int s = (((kc * 4 + kg) ^ (row & 7)) << 3);
          bf16x8 vf = *(const bf16x8*)&VT[row * 64 + s];
          o[njd] = __builtin_amdgcn_mfma_f32_16x16x32_bf16(pa, vf, o[njd], 0, 0, 0);
        }
      }

      __syncthreads();
      cur ^= 1;
    }

    // --- epilogue: O /= l, write bf16 to Y [B,T,C] ---
#pragma unroll
    for (int jj = 0; jj < 4; ++jj) {
      float inv = 1.0f / l_[jj];
      int q = qrow0 + kg * 4 + jj;
      uint16_t* yp = Y + ((size_t)(b * T_ + q)) * C_ + h * HD_;
#pragma unroll
      for (int njd = 0; njd < 4; ++njd)
        yp[njd * 16 + l16] = f2b(o[njd][jj] * inv);
    }
  }
}

extern "C" void kernel_launch(void* const* d_in, const int* in_sizes, int n_in,
                              void* d_out, int out_size, void* d_ws, size_t ws_size,
                              hipStream_t stream) {
  const float* x      = (const float*)d_in[0];
  const float* W_attn = (const float*)d_in[1];
  const float* b_attn = (const float*)d_in[2];
  const float* W_proj = (const float*)d_in[3];
  const float* b_proj = (const float*)d_in[4];
  float* out = (float*)d_out;

  char* ws = (char*)d_ws;
  uint16_t* xb  = (uint16_t*)(ws);
  uint16_t* WtA = (uint16_t*)(ws + 12582912);
  uint16_t* WtP = (uint16_t*)(ws + 16121856);
  uint16_t* QKV = (uint16_t*)(ws + 17301504);
  uint16_t* Yb  = (uint16_t*)(ws + 55050240);

  uint16_t* Qp = QKV;
  uint16_t* Kp = QKV + 6291456;
  uint16_t* Vp = QKV + 12582912;  // [B,H,64,T]

  k_cvt<<<6144, 256, 0, stream>>>(x, xb, 1572864);
  k_tr<<<dim3(72, 24), dim3(32, 8), 0, stream>>>(W_attn, WtA, 768, 2304);
  k_tr<<<dim3(24, 24), dim3(32, 8), 0, stream>>>(W_proj, WtP, 768, 768);
  k_gemm<1><<<dim3(64, 18), 256, 0, stream>>>(xb, WtA, b_attn, nullptr, QKV, 8192, 2304, 768);
  k_attn2<<<dim3(16, 12, 4), 256, 0, stream>>>(Qp, Kp, Vp, Yb);
  k_gemm<0><<<dim3(64, 6), 256, 0, stream>>>(Yb, WtP, b_proj, out, nullptr, 8192, 768, 768);
}

// Round 4
// 179.923 us; speedup vs baseline: 12.8864x; 1.0348x over previous
//
#include <hip/hip_runtime.h>
#include <hip/hip_bf16.h>
#include <cstdint>

#define B_  4
#define T_  2048
#define C_  768
#define H_  12
#define HD_ 64

#define AS1 __attribute__((address_space(1)))
#define AS3 __attribute__((address_space(3)))

typedef float    f32x4  __attribute__((ext_vector_type(4)));
typedef __bf16   bf16x8 __attribute__((ext_vector_type(8)));
typedef uint32_t u32x4  __attribute__((ext_vector_type(4)));

// log2(e)/8: folded into Q at GEMM1 epilogue -> softmax runs in exp2 domain.
#define QSCL 0.18033688011112042f

__device__ __forceinline__ uint16_t f2b(float f) {   // native RNE cvt
  __bf16 h = (__bf16)f;
  return __builtin_bit_cast(uint16_t, h);
}
__device__ __forceinline__ uint32_t pk2(float a, float b) {
  return (uint32_t)f2b(a) | ((uint32_t)f2b(b) << 16);
}

// ---------------- fp32 -> bf16 cast (vectorized) ----------------
__global__ void k_cvt(const float* __restrict__ in, uint16_t* __restrict__ out, int n4) {
  int i = blockIdx.x * blockDim.x + threadIdx.x;
  if (i >= n4) return;
  float4 v = ((const float4*)in)[i];
  uint2 o;
  o.x = pk2(v.x, v.y);
  o.y = pk2(v.z, v.w);
  ((uint2*)out)[i] = o;
}

// ------- transpose + cast: in fp32 [R][Cc] -> out bf16 [Cc][R] -------
__global__ void k_tr(const float* __restrict__ in, uint16_t* __restrict__ out, int R, int Cc) {
  __shared__ float tile[32][33];
  int n0 = blockIdx.x * 32, k0 = blockIdx.y * 32;
  int tx = threadIdx.x, ty = threadIdx.y;  // (32,8)
#pragma unroll
  for (int i = 0; i < 32; i += 8)
    tile[ty + i][tx] = in[(size_t)(k0 + ty + i) * Cc + n0 + tx];
  __syncthreads();
#pragma unroll
  for (int i = 0; i < 32; i += 8)
    out[(size_t)(n0 + ty + i) * R + k0 + tx] = f2b(tile[tx][ty + i]);
}

// ---------------- MFMA bf16 GEMM: C = A[M,K] * Bt[N,K]^T + bias ----------------
// global_load_lds (16B) staging into linear 64B rows, 4-slot XOR swizzle, dbuf,
// 1 barrier per k-step. EPI 0: fp32 [M,N]. EPI 1: scatter bf16 QKV; Q scaled by
// QSCL; V stored transposed [B,H,64,T].
template <int EPI>
__global__ __launch_bounds__(256, 2) void k_gemm(
    const uint16_t* __restrict__ A, const uint16_t* __restrict__ Bt,
    const float* __restrict__ bias, float* __restrict__ outF,
    uint16_t* __restrict__ outQKV, int M, int N, int K) {
  __shared__ __align__(16) uint16_t As[2][128 * 32];
  __shared__ __align__(16) uint16_t Bs[2][128 * 32];
  const int tid  = threadIdx.x;
  const int lane = tid & 63;
  const int wave = tid >> 6;
  const int wrow = (wave >> 1) * 64, wcol = (wave & 1) * 64;
  const int rowBase = blockIdx.x * 128, colBase = blockIdx.y * 128;
  const int l16 = lane & 15, kg = lane >> 4;

  f32x4 acc[4][4];
#pragma unroll
  for (int i = 0; i < 4; ++i)
#pragma unroll
    for (int j = 0; j < 4; ++j) acc[i][j] = (f32x4){0.f, 0.f, 0.f, 0.f};

  // staging geometry: per issue i, wave stages 16 rows (i*64 + wave*16 .. +15).
  const int srow  = lane >> 2;            // row within 16-row group
  const int sslot = lane & 3;             // 16B slot
  const int ssw   = (sslot ^ (srow & 3)) << 3;  // swizzled src elem offset

  auto STAGE = [&](int buf, int k0) {
#pragma unroll
    for (int i = 0; i < 2; ++i) {
      const int r = i * 64 + wave * 16 + srow;
      const uint16_t* srcA = A  + (size_t)(rowBase + r) * K + k0 + ssw;
      const uint16_t* srcB = Bt + (size_t)(colBase + r) * K + k0 + ssw;
      uint16_t* dstA = &As[buf][(i * 64 + wave * 16) * 32];
      uint16_t* dstB = &Bs[buf][(i * 64 + wave * 16) * 32];
      __builtin_amdgcn_global_load_lds((const AS1 uint32_t*)srcA, (AS3 uint32_t*)dstA, 16, 0, 0);
      __builtin_amdgcn_global_load_lds((const AS1 uint32_t*)srcB, (AS3 uint32_t*)dstB, 16, 0, 0);
    }
  };

  const int sA = (kg ^ (l16 & 3)) << 3;   // swizzled frag-read elem offset

  STAGE(0, 0);
  int cur = 0;
  for (int k0 = 0; k0 < K; k0 += 32) {
    __syncthreads();                      // drains DMA into cur + protects overwrite
    if (k0 + 32 < K) STAGE(cur ^ 1, k0 + 32);
    bf16x8 af[4], bfv[4];
#pragma unroll
    for (int mi = 0; mi < 4; ++mi)
      af[mi] = *(const bf16x8*)&As[cur][(wrow + mi * 16 + l16) * 32 + sA];
#pragma unroll
    for (int nj = 0; nj < 4; ++nj)
      bfv[nj] = *(const bf16x8*)&Bs[cur][(wcol + nj * 16 + l16) * 32 + sA];
#pragma unroll
    for (int mi = 0; mi < 4; ++mi)
#pragma unroll
      for (int nj = 0; nj < 4; ++nj)
        acc[mi][nj] = __builtin_amdgcn_mfma_f32_16x16x32_bf16(af[mi], bfv[nj], acc[mi][nj], 0, 0, 0);
    cur ^= 1;
  }

  const int rg = lane >> 4;
#pragma unroll
  for (int mi = 0; mi < 4; ++mi)
#pragma unroll
    for (int nj = 0; nj < 4; ++nj) {
      int c = colBase + wcol + nj * 16 + l16;
      float bv = bias[c];
#pragma unroll
      for (int jj = 0; jj < 4; ++jj) {
        int r = rowBase + wrow + mi * 16 + rg * 4 + jj;
        float v = acc[mi][nj][jj] + bv;
        if (EPI == 0) {
          outF[(size_t)r * N + c] = v;
        } else {
          int sel = c / 768;
          int rem = c - sel * 768;
          int head = rem >> 6, d = rem & 63;
          int bb = r >> 11, tt = r & 2047;
          size_t off;
          if (sel == 2)  // V transposed: [B,H,64,T]
            off = (((size_t)2 * (B_ * H_) + bb * H_ + head) * HD_ + d) * T_ + tt;
          else
            off = (((size_t)sel * (B_ * H_) + bb * H_ + head) * T_ + tt) * HD_ + d;
          if (sel == 0) v *= QSCL;  // pre-scale Q (log2-domain softmax)
          outQKV[off] = f2b(v);
        }
      }
    }
}

// ---------------- MFMA flash attention, v3 ----------------
// grid (16, 12, 4); 4 waves; block px handles q-blocks {px, 31-px}. KV tiles of 64
// DMA-staged (swizzled source / swizzled read), dbuf, 1 barrier/tile. Softmax in
// exp2 domain (Q pre-scaled), diag-only masking, deferred l-reduce, T13 defer-
// rescale (THR=8 log2), native bf16 cvt, setprio around MFMA.
#define LDP 72
__global__ __launch_bounds__(256, 3) void k_attn2(
    const uint16_t* __restrict__ Qb, const uint16_t* __restrict__ Kb,
    const uint16_t* __restrict__ Vb, uint16_t* __restrict__ Y) {
  __shared__ __align__(16) uint16_t Ks[2][64 * 64];
  __shared__ __align__(16) uint16_t Vs[2][64 * 64];
  __shared__ __align__(16) uint16_t Ps[4][16 * LDP];
  const int tid  = threadIdx.x;
  const int lane = tid & 63;
  const int wq   = tid >> 6;
  const int l16  = lane & 15, kg = lane >> 4;
  const int px = blockIdx.x, h = blockIdx.y, b = blockIdx.z;
  const size_t headBase = ((size_t)(b * H_ + h)) * (size_t)(T_ * HD_);

  const int srow0 = wq * 16 + (lane >> 3);
  const int sslot = lane & 7;

  uint16_t* pw = &Ps[wq][0];

  auto STAGE = [&](int buf, int t) {
    const int kvoff = t * 64;
#pragma unroll
    for (int j = 0; j < 2; ++j) {
      const int r  = srow0 + j * 8;
      const int sw = ((sslot ^ (r & 7)) << 3);
      const uint16_t* srcK = Kb + headBase + (size_t)(kvoff + r) * HD_ + sw;
      const uint16_t* srcV = Vb + headBase + (size_t)r * T_ + kvoff + sw;
      uint16_t* dstK = &Ks[buf][(wq * 16 + j * 8) * 64];
      uint16_t* dstV = &Vs[buf][(wq * 16 + j * 8) * 64];
      __builtin_amdgcn_global_load_lds((const AS1 uint32_t*)srcK, (AS3 uint32_t*)dstK, 16, 0, 0);
      __builtin_amdgcn_global_load_lds((const AS1 uint32_t*)srcV, (AS3 uint32_t*)dstV, 16, 0, 0);
    }
  };

  for (int part = 0; part < 2; ++part) {
    const int qb = part ? (31 - px) : px;
    const int qrow0 = qb * 64 + wq * 16;

    bf16x8 qf[2];
    {
      const uint16_t* qp = Qb + headBase + (size_t)(qrow0 + l16) * HD_;
      qf[0] = *(const bf16x8*)(qp + kg * 8);
      qf[1] = *(const bf16x8*)(qp + 32 + kg * 8);
    }

    f32x4 o[4];
#pragma unroll
    for (int i = 0; i < 4; ++i) o[i] = (f32x4){0.f, 0.f, 0.f, 0.f};
    float m_[4], l_[4];
#pragma unroll
    for (int jj = 0; jj < 4; ++jj) { m_[jj] = -__builtin_inff(); l_[jj] = 0.f; }

    const int nt = qb + 1;
    STAGE(0, 0);
    int cur = 0;

    for (int t = 0; t < nt; ++t) {
      __syncthreads();                    // drains DMA into cur
      if (t + 1 < nt) STAGE(cur ^ 1, t + 1);

      const uint16_t* KT = &Ks[cur][0];
      const uint16_t* VT = &Vs[cur][0];

      // --- S = Q K^T (16 q x 64 kv per wave), already in log2 units ---
      f32x4 sm[4];
      __builtin_amdgcn_s_setprio(1);
#pragma unroll
      for (int nj = 0; nj < 4; ++nj) {
        f32x4 acc = (f32x4){0.f, 0.f, 0.f, 0.f};
#pragma unroll
        for (int kc = 0; kc < 2; ++kc) {
          const int row = nj * 16 + l16;
          const int s = (((kc * 4 + kg) ^ (row & 7)) << 3);
          bf16x8 kf = *(const bf16x8*)&KT[row * 64 + s];
          acc = __builtin_amdgcn_mfma_f32_16x16x32_bf16(qf[kc], kf, acc, 0, 0, 0);
        }
        sm[nj] = acc;
      }
      __builtin_amdgcn_s_setprio(0);

      if (t == qb) {  // diagonal tile: causal mask (wave-uniform branch)
        const int kvoff = t * 64;
#pragma unroll
        for (int nj = 0; nj < 4; ++nj) {
          int kvg = kvoff + nj * 16 + l16;
#pragma unroll
          for (int jj = 0; jj < 4; ++jj) {
            int qg = qrow0 + kg * 4 + jj;
            if (kvg > qg) sm[nj][jj] = -__builtin_inff();
          }
        }
      }

      // --- online softmax (exp2 domain; row = kg*4+jj) ---
#pragma unroll
      for (int jj = 0; jj < 4; ++jj) {
        float v = fmaxf(fmaxf(sm[0][jj], sm[1][jj]), fmaxf(sm[2][jj], sm[3][jj]));
        v = fmaxf(v, __shfl_xor(v, 1));
        v = fmaxf(v, __shfl_xor(v, 2));
        v = fmaxf(v, __shfl_xor(v, 4));
        v = fmaxf(v, __shfl_xor(v, 8));
        if (__ballot(v > m_[jj] + 8.0f) != 0ull) {  // T13: rescale only on growth
          float mn = fmaxf(m_[jj], v);
          float corr = __builtin_exp2f(m_[jj] - mn);
          m_[jj] = mn;
          l_[jj] *= corr;
#pragma unroll
          for (int njd = 0; njd < 4; ++njd) o[njd][jj] *= corr;
        }
        float mj = m_[jj];
        float ps = 0.f;
#pragma unroll
        for (int nj = 0; nj < 4; ++nj) {
          float p = __builtin_exp2f(sm[nj][jj] - mj);
          sm[nj][jj] = p;
          ps += p;
        }
        l_[jj] += ps;  // per-lane partial; reduced in epilogue
      }

      // --- P -> per-wave LDS buffer, reload as A-fragments ---
#pragma unroll
      for (int nj = 0; nj < 4; ++nj)
#pragma unroll
        for (int jj = 0; jj < 4; ++jj)
          pw[(kg * 4 + jj) * LDP + nj * 16 + l16] = f2b(sm[nj][jj]);

      // --- O += P V ---
      __builtin_amdgcn_s_setprio(1);
#pragma unroll
      for (int kc = 0; kc < 2; ++kc) {
        bf16x8 pa = *(const bf16x8*)&pw[l16 * LDP + kc * 32 + kg * 8];
#pragma unroll
        for (int njd = 0; njd < 4; ++njd) {
          const int row = njd * 16 + l16;
          const int s = (((kc * 4 + kg) ^ (row & 7)) << 3);
          bf16x8 vf = *(const bf16x8*)&VT[row * 64 + s];
          o[njd] = __builtin_amdgcn_mfma_f32_16x16x32_bf16(pa, vf, o[njd], 0, 0, 0);
        }
      }
      __builtin_amdgcn_s_setprio(0);

      __syncthreads();
      cur ^= 1;
    }

    // --- epilogue: reduce l across 16-lane group, O /= l, write bf16 ---
#pragma unroll
    for (int jj = 0; jj < 4; ++jj) {
      float lf = l_[jj];
      lf += __shfl_xor(lf, 1);
      lf += __shfl_xor(lf, 2);
      lf += __shfl_xor(lf, 4);
      lf += __shfl_xor(lf, 8);
      float inv = __builtin_amdgcn_rcpf(lf);
      int q = qrow0 + kg * 4 + jj;
      uint16_t* yp = Y + ((size_t)(b * T_ + q)) * C_ + h * HD_;
#pragma unroll
      for (int njd = 0; njd < 4; ++njd)
        yp[njd * 16 + l16] = f2b(o[njd][jj] * inv);
    }
  }
}

extern "C" void kernel_launch(void* const* d_in, const int* in_sizes, int n_in,
                              void* d_out, int out_size, void* d_ws, size_t ws_size,
                              hipStream_t stream) {
  const float* x      = (const float*)d_in[0];
  const float* W_attn = (const float*)d_in[1];
  const float* b_attn = (const float*)d_in[2];
  const float* W_proj = (const float*)d_in[3];
  const float* b_proj = (const float*)d_in[4];
  float* out = (float*)d_out;

  char* ws = (char*)d_ws;
  uint16_t* xb  = (uint16_t*)(ws);
  uint16_t* WtA = (uint16_t*)(ws + 12582912);
  uint16_t* WtP = (uint16_t*)(ws + 16121856);
  uint16_t* QKV = (uint16_t*)(ws + 17301504);
  uint16_t* Yb  = (uint16_t*)(ws + 55050240);

  uint16_t* Qp = QKV;                // pre-scaled by QSCL
  uint16_t* Kp = QKV + 6291456;
  uint16_t* Vp = QKV + 12582912;     // [B,H,64,T]

  k_cvt<<<6144, 256, 0, stream>>>(x, xb, 1572864);
  k_tr<<<dim3(72, 24), dim3(32, 8), 0, stream>>>(W_attn, WtA, 768, 2304);
  k_tr<<<dim3(24, 24), dim3(32, 8), 0, stream>>>(W_proj, WtP, 768, 768);
  k_gemm<1><<<dim3(64, 18), 256, 0, stream>>>(xb, WtA, b_attn, nullptr, QKV, 8192, 2304, 768);
  k_attn2<<<dim3(16, 12, 4), 256, 0, stream>>>(Qp, Kp, Vp, Yb);
  k_gemm<0><<<dim3(64, 6), 256, 0, stream>>>(Yb, WtP, b_proj, out, nullptr, 8192, 768, 768);
}